// Round 4
// baseline (8071.949 us; speedup 1.0000x reference)
//
#include <hip/hip_runtime.h>
#include <hip/hip_bf16.h>

#define S_LEN 60
#define BATCH 256
#define EMB   300
#define EMBP  320              /* padded K for proj & x-part (zero cols 300..319) */
#define HID   512
#define DMLP  1024
#define NROW  (2*S_LEN*BATCH)  /* 30720 */
#define RPS   (S_LEN*BATCH)    /* 15360 */

typedef __attribute__((ext_vector_type(8))) short short8v;
typedef __attribute__((ext_vector_type(4))) float f32x4;

static __device__ __forceinline__ float sigf(float x){
  return 1.0f/(1.0f+__expf(-x));
}
static __device__ __forceinline__ float tanh_fast(float x){
  x = fminf(fmaxf(x,-40.0f),40.0f);
  float a = __expf(2.0f*x);
  return (a-1.0f)/(a+1.0f);
}
static __device__ __forceinline__ unsigned short f2b(float v){
  __hip_bfloat16 h = __float2bfloat16(v);
  return *(unsigned short*)&h;
}
static __device__ __forceinline__ float b2f(unsigned short u){
  return __uint_as_float(((unsigned int)u)<<16);
}

// ---------------------------------------------------------------------------
// K-conv: weights -> bf16 (Wih & projW padded), bsum = bih+bhh
// ---------------------------------------------------------------------------
__global__ __launch_bounds__(256) void k_conv_weights(
    const float* __restrict__ Wih, const float* __restrict__ Whh,
    const float* __restrict__ bih, const float* __restrict__ bhh,
    const float* __restrict__ projW,
    unsigned short* __restrict__ Wihb, unsigned short* __restrict__ Whhb,
    unsigned short* __restrict__ projWb, float* __restrict__ bsum)
{
  const int tid = blockIdx.x*256 + threadIdx.x;
  const int stride = gridDim.x*256;
  for (int i=tid; i<2048*EMBP; i+=stride){
    int n = i/EMBP, k = i - n*EMBP;
    Wihb[i] = f2b((k<EMB) ? Wih[(size_t)n*EMB + k] : 0.0f);
  }
  for (int i=tid; i<2048*HID; i+=stride) Whhb[i] = f2b(Whh[i]);
  for (int i=tid; i<EMBP*EMBP; i+=stride){
    int n = i/EMBP, k = i - n*EMBP;
    projWb[i] = f2b((n<EMB && k<EMB) ? projW[(size_t)n*EMB + k] : 0.0f);
  }
  for (int i=tid; i<2048; i+=stride) bsum[i] = bih[i]+bhh[i];
}

// ---------------------------------------------------------------------------
// K1: embedding gather + projection GEMM via MFMA -> bf16 P [30720][320]
// ---------------------------------------------------------------------------
__global__ __launch_bounds__(512) void k_embed_mfma(
    const float* __restrict__ embed, const unsigned short* __restrict__ projWb,
    const float* __restrict__ projb, const int* __restrict__ s1,
    const int* __restrict__ s2, unsigned short* __restrict__ Pb)
{
  __shared__ __align__(16) unsigned short sA0[64*40];
  __shared__ __align__(16) unsigned short sA1[64*40];
  __shared__ __align__(16) unsigned short sW0[64*40];
  __shared__ __align__(16) unsigned short sW1[64*40];
  __shared__ int stok[64];
  const int m0 = blockIdx.x*64, n0 = blockIdx.y*64;
  const int tid = threadIdx.x;
  if (tid < 64){
    int r = m0 + tid;
    stok[tid] = (r < RPS) ? s1[r] : s2[r-RPS];
  }
  __syncthreads();
  const int lane = tid & 63, w = tid>>6;
  const int wr = w>>2, wc = w&3;
  const bool isA = tid < 256;
  const int srow = (tid&255)>>2, sseg = tid&3;
  const float* Arow = embed + (size_t)stok[srow]*EMB;
  const unsigned short* Wrow = projWb + (size_t)(n0+srow)*EMBP;

  const int ldst = srow*40 + sseg*8;
  const int aoff0 = (wr*32 + (lane&15))*40 + (lane>>4)*8;
  const int aoff1 = aoff0 + 16*40;
  const int woff  = (wc*16 + (lane&15))*40 + (lane>>4)*8;

  f32x4 acc0 = {0.f,0.f,0.f,0.f}, acc1 = {0.f,0.f,0.f,0.f};

  auto loadA = [&](int kk)->uint4 {
    int kb = kk*32 + sseg*8;
    unsigned short t8[8];
    if (kb+7 < EMB){
      float4 f0 = *(const float4*)(Arow + kb);
      float4 f1 = *(const float4*)(Arow + kb + 4);
      t8[0]=f2b(f0.x); t8[1]=f2b(f0.y); t8[2]=f2b(f0.z); t8[3]=f2b(f0.w);
      t8[4]=f2b(f1.x); t8[5]=f2b(f1.y); t8[6]=f2b(f1.z); t8[7]=f2b(f1.w);
    } else {
      #pragma unroll
      for (int jq=0; jq<8; jq++){
        int k = kb+jq;
        t8[jq] = f2b((k<EMB) ? Arow[k] : 0.0f);
      }
    }
    uint4 o;
    o.x = (unsigned)t8[0] | ((unsigned)t8[1]<<16);
    o.y = (unsigned)t8[2] | ((unsigned)t8[3]<<16);
    o.z = (unsigned)t8[4] | ((unsigned)t8[5]<<16);
    o.w = (unsigned)t8[6] | ((unsigned)t8[7]<<16);
    return o;
  };

  if (isA) *(uint4*)(sA0 + ldst) = loadA(0);
  else     *(uint4*)(sW0 + ldst) = *(const uint4*)(Wrow + sseg*8);
  __syncthreads();

  for (int kk=0; kk<10; kk++){
    uint4 nv;
    if (kk < 9){
      if (isA) nv = loadA(kk+1);
      else     nv = *(const uint4*)(Wrow + (kk+1)*32 + sseg*8);
    }
    const unsigned short* A = (kk&1) ? sA1 : sA0;
    const unsigned short* W = (kk&1) ? sW1 : sW0;
    short8v af0 = *(const short8v*)(A + aoff0);
    short8v af1 = *(const short8v*)(A + aoff1);
    short8v wf  = *(const short8v*)(W + woff);
    acc0 = __builtin_amdgcn_mfma_f32_16x16x32_bf16(af0, wf, acc0, 0,0,0);
    acc1 = __builtin_amdgcn_mfma_f32_16x16x32_bf16(af1, wf, acc1, 0,0,0);
    if (kk < 9){
      unsigned short* dst = ((kk&1) ? (isA?sA0:sW0) : (isA?sA1:sW1)) + ldst;
      *(uint4*)dst = nv;
    }
    __syncthreads();
  }

  const int cc = wc*16 + (lane&15);
  const int n = n0 + cc;
  const float bias = (n < EMB) ? projb[n] : 0.0f;
  const bool valid = (n < EMB);
  #pragma unroll
  for (int v=0; v<4; v++){
    int r0 = wr*32 + (lane>>4)*4 + v;
    Pb[(size_t)(m0+r0)*EMBP + n]    = f2b(valid ? acc0[v]+bias : 0.0f);
    Pb[(size_t)(m0+r0+16)*EMBP + n] = f2b(valid ? acc1[v]+bias : 0.0f);
  }
}

// ---------------------------------------------------------------------------
// K2: BN partial sums over bf16 P
// ---------------------------------------------------------------------------
__global__ __launch_bounds__(320) void k_bn_partial(const unsigned short* __restrict__ Pb,
    float* __restrict__ ps, float* __restrict__ psq)
{
  const int rb = blockIdx.x, sent = blockIdx.y, t = threadIdx.x;
  if (t >= EMB) return;
  const unsigned short* base = Pb + ((size_t)sent*RPS + (size_t)rb*256)*EMBP;
  float s=0.0f, q=0.0f;
  for (int r=0;r<256;r++){
    float v = b2f(base[(size_t)r*EMBP + t]);
    s += v; q = fmaf(v,v,q);
  }
  ps [(size_t)(sent*60+rb)*EMB + t] = s;
  psq[(size_t)(sent*60+rb)*EMB + t] = q;
}

__global__ __launch_bounds__(320) void k_bn_final(const float* __restrict__ ps,
    const float* __restrict__ psq, const float* __restrict__ g,
    const float* __restrict__ b, float* __restrict__ scale, float* __restrict__ shift)
{
  const int sent = blockIdx.x, t = threadIdx.x;
  if (t >= EMB) return;
  float s=0.0f, q=0.0f;
  for (int i=0;i<60;i++){
    s += ps [(size_t)(sent*60+i)*EMB + t];
    q += psq[(size_t)(sent*60+i)*EMB + t];
  }
  float mean = s * (1.0f/15360.0f);
  float var  = q * (1.0f/15360.0f) - mean*mean;
  float sc = g[t] * rsqrtf(var + 1e-5f);
  scale[sent*EMB+t] = sc;
  shift[sent*EMB+t] = b[t] - mean*sc;
}

__global__ __launch_bounds__(256) void k_bn_apply(unsigned short* __restrict__ Pb,
    const float* __restrict__ scale, const float* __restrict__ shift)
{
  const int r = blockIdx.x*8 + (threadIdx.x>>5);
  const int c0 = threadIdx.x & 31;
  const int sent = (r >= RPS) ? 1 : 0;
  unsigned short* row = Pb + (size_t)r*EMBP;
  for (int c=c0; c<EMB; c+=32){
    float v = b2f(row[c]);
    v = fmaf(v, scale[sent*EMB+c], shift[sent*EMB+c]);
    row[c] = f2b(v);
  }
}

// ---------------------------------------------------------------------------
// K4: self-contained persistent LSTM. 32 blocks x 512 thr; block owns 16 rows
// and computes ALL 2048 gate-cols -> no cross-block dependency, no grid.sync,
// single dispatch. h in LDS, c in regs, W streamed from L2 per step.
//  - A-buf: [16 rows][840] ush  (cols 0..319 = x_t, 320..831 = h_{t-1})
//  - zs:    [16 rows][2052] f32 (z scatter buffer)
//  - wave w computes gate-cols [w*256, w*256+256): 16 j-tiles x (10+16) k-iters
// ---------------------------------------------------------------------------
#define ABST 840   /* ush stride; 1680B = 16B-mult; banks 4r%32 -> 2-way (free) */
#define ZST  2052  /* f32 stride; 8208B = 16B-mult; scatter 2-way (free) */

__global__ __launch_bounds__(512) void k_lstm_fused(
    const unsigned short* __restrict__ Pb,    // [30720][320]
    const unsigned short* __restrict__ Wihb,  // [2048][320]
    const unsigned short* __restrict__ Whhb,  // [2048][512]
    const float* __restrict__ bsum,           // [2048]
    unsigned short* __restrict__ Hout)        // [2][60][256][512]
{
  __shared__ __align__(16) char smem[16*ABST*2 + 16*ZST*4];   // 26880+131328=158208
  unsigned short* ab = (unsigned short*)smem;
  float* zs = (float*)(smem + 16*ABST*2);

  const int tid = threadIdx.x;
  const int lane = tid & 63, w = tid >> 6;
  const int m0 = blockIdx.x * 16;
  const int sent = m0 >> 8;
  const int brow = m0 & 255;

  // epilogue ownership: 4 rows x 4 consecutive j per thread
  const int jb = tid & 127;
  const int j0e = jb * 4;
  const int rg = tid >> 7;

  float bb[4][4];
  #pragma unroll
  for (int g=0; g<4; g++)
    #pragma unroll
    for (int jj=0; jj<4; jj++)
      bb[g][jj] = bsum[g*HID + j0e + jj];

  float cs[4][4];
  #pragma unroll
  for (int a=0;a<4;a++)
    #pragma unroll
    for (int c=0;c<4;c++) cs[a][c] = 0.0f;

  // zero h-region of ab (cols 320..831): 16 rows x 512 ush = 1024 uint4
  for (int i = tid; i < 1024; i += 512){
    int r = i >> 6, c = (i & 63) * 8;
    uint4 z = {0,0,0,0};
    *(uint4*)(ab + r*ABST + 320 + c) = z;
  }

  // MFMA fragment addressing
  const int arow = lane & 15;            // A row / B col
  const int aks  = (lane >> 4) * 8;      // k sub-offset
  const unsigned short* abA = ab + arow*ABST + aks;
  const int jw = w * 256;                // this wave's gate-col base
  const unsigned short* WihL = Wihb + (size_t)(jw + arow)*EMBP + aks;
  const unsigned short* WhhL = Whhb + (size_t)(jw + arow)*HID  + aks;

  for (int t=0; t<S_LEN; t++){
    // stage x_t rows (16 x 320 ush) into ab cols 0..319
    const unsigned short* Prow = Pb + ((size_t)((sent*S_LEN + t)*BATCH) + brow)*EMBP;
    for (int i = tid; i < 640; i += 512){
      int r = i / 40, c = (i - r*40) * 8;
      *(uint4*)(ab + r*ABST + c) = *(const uint4*)(Prow + (size_t)r*EMBP + c);
    }
    __syncthreads();

    f32x4 acc[16];
    #pragma unroll
    for (int jt=0;jt<16;jt++){ f32x4 z = {0.f,0.f,0.f,0.f}; acc[jt] = z; }

    // x @ Wih^T  (K = 320)
    for (int kk=0; kk<10; kk++){
      short8v a = *(const short8v*)(abA + kk*32);
      #pragma unroll
      for (int h=0; h<2; h++){
        short8v bfr[8];
        #pragma unroll
        for (int u=0;u<8;u++)
          bfr[u] = *(const short8v*)(WihL + (size_t)(h*8+u)*16*EMBP + kk*32);
        #pragma unroll
        for (int u=0;u<8;u++)
          acc[h*8+u] = __builtin_amdgcn_mfma_f32_16x16x32_bf16(a, bfr[u], acc[h*8+u], 0,0,0);
      }
    }
    // h @ Whh^T  (K = 512)
    for (int kk=0; kk<16; kk++){
      short8v a = *(const short8v*)(abA + 320 + kk*32);
      #pragma unroll
      for (int h=0; h<2; h++){
        short8v bfr[8];
        #pragma unroll
        for (int u=0;u<8;u++)
          bfr[u] = *(const short8v*)(WhhL + (size_t)(h*8+u)*16*HID + kk*32);
        #pragma unroll
        for (int u=0;u<8;u++)
          acc[h*8+u] = __builtin_amdgcn_mfma_f32_16x16x32_bf16(a, bfr[u], acc[h*8+u], 0,0,0);
      }
    }

    // scatter z -> zs
    #pragma unroll
    for (int jt=0;jt<16;jt++){
      int col = jw + jt*16 + arow;
      #pragma unroll
      for (int v=0;v<4;v++){
        int row = (lane>>4)*4 + v;
        zs[row*ZST + col] = acc[jt][v];
      }
    }
    __syncthreads();

    // cell update: 4 rows x 4 j per thread; c in regs; h -> ab + Hout
    unsigned short* HoutT = Hout + ((size_t)((sent*S_LEN + t)*BATCH) + brow)*HID;
    #pragma unroll
    for (int ri=0; ri<4; ri++){
      int row = rg*4 + ri;
      float4 zi4 = *(const float4*)&zs[row*ZST + 0*HID + j0e];
      float4 zf4 = *(const float4*)&zs[row*ZST + 1*HID + j0e];
      float4 zg4 = *(const float4*)&zs[row*ZST + 2*HID + j0e];
      float4 zo4 = *(const float4*)&zs[row*ZST + 3*HID + j0e];
      float zi_a[4] = {zi4.x, zi4.y, zi4.z, zi4.w};
      float zf_a[4] = {zf4.x, zf4.y, zf4.z, zf4.w};
      float zg_a[4] = {zg4.x, zg4.y, zg4.z, zg4.w};
      float zo_a[4] = {zo4.x, zo4.y, zo4.z, zo4.w};
      unsigned int hlo = 0, hhi = 0;
      #pragma unroll
      for (int jj=0; jj<4; jj++){
        float zi = zi_a[jj] + bb[0][jj];
        float zf = zf_a[jj] + bb[1][jj];
        float zg = zg_a[jj] + bb[2][jj];
        float zo = zo_a[jj] + bb[3][jj];
        float cn = fmaf(sigf(zf), cs[ri][jj], sigf(zi)*tanh_fast(zg));
        cs[ri][jj] = cn;
        float hn = sigf(zo)*tanh_fast(cn);
        unsigned int hb = f2b(hn);
        if (jj < 2) hlo |= hb << (16*jj);
        else        hhi |= hb << (16*(jj-2));
      }
      uint2 hv = {hlo, hhi};
      *(uint2*)(ab + row*ABST + 320 + j0e) = hv;
      *(uint2*)(HoutT + (size_t)row*HID + j0e) = hv;
    }
    __syncthreads();
  }
}

// ---------------------------------------------------------------------------
// K5: fused pairwise-L2-distance + 15x15 min-pool
// ---------------------------------------------------------------------------
#define SDU 258
__global__ __launch_bounds__(256) void k_dist_pool(
    const unsigned short* __restrict__ Hout, float* __restrict__ pooled)
{
  __shared__ unsigned int h1s[S_LEN*SDU];
  __shared__ unsigned int h2s[S_LEN*SDU];
  __shared__ float n1s[S_LEN], n2s[S_LEN];
  const int b = blockIdx.x, tid = threadIdx.x;
  const unsigned int* H = (const unsigned int*)Hout;
  for (int e=tid; e<S_LEN*256; e+=256){
    int row = e>>8, cu = e&255;
    h1s[row*SDU+cu] = H[((size_t)(0*S_LEN+row)*BATCH + b)*256 + cu];
    h2s[row*SDU+cu] = H[((size_t)(1*S_LEN+row)*BATCH + b)*256 + cu];
  }
  __syncthreads();
  if (tid < S_LEN){
    const unsigned int* rp = &h1s[tid*SDU];
    float q=0.0f;
    for (int cu=0;cu<256;cu++){
      unsigned int u = rp[cu];
      float lo = __uint_as_float(u<<16);
      float hi = __uint_as_float(u & 0xffff0000u);
      q = fmaf(lo,lo,q); q = fmaf(hi,hi,q);
    }
    n1s[tid] = q;
  } else if (tid >= 64 && tid < 64+S_LEN){
    const unsigned int* rp = &h2s[(tid-64)*SDU];
    float q=0.0f;
    for (int cu=0;cu<256;cu++){
      unsigned int u = rp[cu];
      float lo = __uint_as_float(u<<16);
      float hi = __uint_as_float(u & 0xffff0000u);
      q = fmaf(lo,lo,q); q = fmaf(hi,hi,q);
    }
    n2s[tid-64] = q;
  }
  __syncthreads();
  if (tid < 225){
    const int gi = tid/15, gj = tid%15;
    float acc[4][4];
    #pragma unroll
    for (int a=0;a<4;a++)
      #pragma unroll
      for (int c=0;c<4;c++) acc[a][c]=0.0f;
    const unsigned int* r1[4]; const unsigned int* r2[4];
    #pragma unroll
    for (int a=0;a<4;a++){ r1[a]=&h1s[(gi*4+a)*SDU]; r2[a]=&h2s[(gj*4+a)*SDU]; }
    for (int cu=0;cu<256;cu++){
      float lo1[4],hi1[4],lo2[4],hi2[4];
      #pragma unroll
      for (int a=0;a<4;a++){
        unsigned int u = r1[a][cu];
        lo1[a]=__uint_as_float(u<<16); hi1[a]=__uint_as_float(u&0xffff0000u);
      }
      #pragma unroll
      for (int c=0;c<4;c++){
        unsigned int u = r2[c][cu];
        lo2[c]=__uint_as_float(u<<16); hi2[c]=__uint_as_float(u&0xffff0000u);
      }
      #pragma unroll
      for (int a=0;a<4;a++)
        #pragma unroll
        for (int c=0;c<4;c++)
          acc[a][c] = fmaf(lo1[a],lo2[c], fmaf(hi1[a],hi2[c], acc[a][c]));
    }
    float mn = 3.4e38f;
    #pragma unroll
    for (int a=0;a<4;a++)
      #pragma unroll
      for (int c=0;c<4;c++){
        float sq = n1s[gi*4+a] + n2s[gj*4+c] - 2.0f*acc[a][c];
        mn = fminf(mn, sqrtf(fmaxf(sq,0.0f)+1e-12f));
      }
    pooled[(size_t)b*225 + tid] = mn;
  }
}

// ---------------------------------------------------------------------------
// MLP kernels
// ---------------------------------------------------------------------------
__global__ __launch_bounds__(256) void k_mlp1(const float* __restrict__ pooled,
    const float* __restrict__ extra, const float* __restrict__ W1,
    const float* __restrict__ b1, float* __restrict__ y1)
{
  __shared__ __align__(16) float xs[232];
  const int b = blockIdx.x, tid = threadIdx.x;
  if (tid < 225) xs[tid] = pooled[(size_t)b*225 + tid];
  else if (tid < 232) xs[tid] = extra[(size_t)b*7 + (tid-225)];
  __syncthreads();
  #pragma unroll
  for (int q=0;q<4;q++){
    int n = tid + q*256;
    float acc = b1[n];
    const float4* wr = (const float4*)(W1 + (size_t)n*232);
    const float4* xr = (const float4*)xs;
    for (int k4=0;k4<58;k4++){
      float4 w = wr[k4]; float4 x = xr[k4];
      acc = fmaf(w.x,x.x, fmaf(w.y,x.y, fmaf(w.z,x.z, fmaf(w.w,x.w, acc))));
    }
    y1[(size_t)b*DMLP + n] = fmaxf(acc, 0.0f);
  }
}

__global__ __launch_bounds__(256) void k_mlp_bn(const float* __restrict__ y,
    const float* __restrict__ g, const float* __restrict__ be,
    float* __restrict__ scale, float* __restrict__ shift)
{
  const int n = blockIdx.x*256 + threadIdx.x;
  float s=0.0f, q=0.0f;
  for (int b=0;b<BATCH;b++){
    float v = y[(size_t)b*DMLP + n];
    s += v; q = fmaf(v,v,q);
  }
  float mean = s * (1.0f/256.0f);
  float var  = q * (1.0f/256.0f) - mean*mean;
  float sc = g[n] * rsqrtf(var + 1e-5f);
  scale[n] = sc;
  shift[n] = be[n] - mean*sc;
}

__global__ __launch_bounds__(256) void k_mlp2(const float* __restrict__ y1,
    const float* __restrict__ scale1, const float* __restrict__ shift1,
    const float* __restrict__ W2, const float* __restrict__ b2,
    float* __restrict__ y2)
{
  __shared__ __align__(16) float xs[4][DMLP];
  const int b0 = blockIdx.x*4, tid = threadIdx.x;
  for (int e=tid; e<4*DMLP; e+=256){
    int bb = e>>10, k = e&1023;
    xs[bb][k] = fmaf(y1[(size_t)(b0+bb)*DMLP + k], scale1[k], shift1[k]);
  }
  __syncthreads();
  #pragma unroll
  for (int q=0;q<4;q++){
    int n = tid + q*256;
    float a0=0.0f,a1=0.0f,a2=0.0f,a3=0.0f;
    const float4* wr = (const float4*)(W2 + (size_t)n*DMLP);
    for (int k4=0;k4<256;k4++){
      float4 w = wr[k4];
      float4 x0 = ((const float4*)xs[0])[k4];
      float4 x1 = ((const float4*)xs[1])[k4];
      float4 x2 = ((const float4*)xs[2])[k4];
      float4 x3 = ((const float4*)xs[3])[k4];
      a0 = fmaf(w.x,x0.x, fmaf(w.y,x0.y, fmaf(w.z,x0.z, fmaf(w.w,x0.w, a0))));
      a1 = fmaf(w.x,x1.x, fmaf(w.y,x1.y, fmaf(w.z,x1.z, fmaf(w.w,x1.w, a1))));
      a2 = fmaf(w.x,x2.x, fmaf(w.y,x2.y, fmaf(w.z,x2.z, fmaf(w.w,x2.w, a2))));
      a3 = fmaf(w.x,x3.x, fmaf(w.y,x3.y, fmaf(w.z,x3.z, fmaf(w.w,x3.w, a3))));
    }
    float bias = b2[n];
    y2[(size_t)(b0+0)*DMLP + n] = fmaxf(a0+bias, 0.0f);
    y2[(size_t)(b0+1)*DMLP + n] = fmaxf(a1+bias, 0.0f);
    y2[(size_t)(b0+2)*DMLP + n] = fmaxf(a2+bias, 0.0f);
    y2[(size_t)(b0+3)*DMLP + n] = fmaxf(a3+bias, 0.0f);
  }
}

__global__ __launch_bounds__(256) void k_mlp3(const float* __restrict__ y2,
    const float* __restrict__ scale2, const float* __restrict__ shift2,
    const float* __restrict__ W3, const float* __restrict__ b3,
    float* __restrict__ out)
{
  __shared__ float r0[256], r1[256];
  const int b = blockIdx.x, tid = threadIdx.x;
  float p0=0.0f, p1=0.0f;
  #pragma unroll
  for (int q=0;q<4;q++){
    int k = tid + q*256;
    float x = fmaf(y2[(size_t)b*DMLP + k], scale2[k], shift2[k]);
    p0 = fmaf(x, W3[k], p0);
    p1 = fmaf(x, W3[DMLP+k], p1);
  }
  r0[tid]=p0; r1[tid]=p1;
  __syncthreads();
  for (int s=128; s>0; s>>=1){
    if (tid<s){ r0[tid]+=r0[tid+s]; r1[tid]+=r1[tid+s]; }
    __syncthreads();
  }
  if (tid==0){
    float l0 = r0[0]+b3[0], l1 = r1[0]+b3[1];
    float m = fmaxf(l0,l1);
    float lse = m + logf(__expf(l0-m)+__expf(l1-m));
    out[b*2+0] = l0-lse;
    out[b*2+1] = l1-lse;
  }
}

// ---------------------------------------------------------------------------
extern "C" void kernel_launch(void* const* d_in, const int* in_sizes, int n_in,
                              void* d_out, int out_size, void* d_ws, size_t ws_size,
                              hipStream_t stream)
{
  (void)in_sizes; (void)n_in; (void)out_size; (void)ws_size;
  const float* embed = (const float*)d_in[0];
  const float* projW = (const float*)d_in[1];
  const float* projb = (const float*)d_in[2];
  const float* bn_g  = (const float*)d_in[3];
  const float* bn_b  = (const float*)d_in[4];
  const float* Wih   = (const float*)d_in[5];
  const float* Whh   = (const float*)d_in[6];
  const float* bih   = (const float*)d_in[7];
  const float* bhh   = (const float*)d_in[8];
  const float* W1    = (const float*)d_in[9];
  const float* b1    = (const float*)d_in[10];
  const float* g1    = (const float*)d_in[11];
  const float* be1   = (const float*)d_in[12];
  const float* W2    = (const float*)d_in[13];
  const float* b2    = (const float*)d_in[14];
  const float* g2    = (const float*)d_in[15];
  const float* be2   = (const float*)d_in[16];
  const float* W3    = (const float*)d_in[17];
  const float* b3    = (const float*)d_in[18];
  const float* extra = (const float*)d_in[19];
  const int*   s1    = (const int*)d_in[20];
  const int*   s2    = (const int*)d_in[21];
  float* out = (float*)d_out;

  float* ws = (float*)d_ws;
  size_t off = 0;
  float* ps   = ws + off; off += (size_t)2*60*EMB;
  float* psq  = ws + off; off += (size_t)2*60*EMB;
  float* bnsc = ws + off; off += 2*EMB;
  float* bnsh = ws + off; off += 2*EMB;
  float* bsum = ws + off; off += 2048;
  unsigned short* Pb     = (unsigned short*)(ws + off); off += (size_t)NROW*EMBP/2;
  unsigned short* Wihb   = (unsigned short*)(ws + off); off += (size_t)2048*EMBP/2;
  unsigned short* Whhb   = (unsigned short*)(ws + off); off += (size_t)2048*HID/2;
  unsigned short* projWb = (unsigned short*)(ws + off); off += (size_t)EMBP*EMBP/2;
  unsigned short* Hout   = (unsigned short*)(ws + off); off += (size_t)2*S_LEN*BATCH*HID/2;
  float* pooled = ws + off; off += (size_t)BATCH*225;
  float* y1     = ws + off; off += (size_t)BATCH*DMLP;
  float* y2     = ws + off; off += (size_t)BATCH*DMLP;
  float* sc1    = ws + off; off += DMLP;
  float* sh1    = ws + off; off += DMLP;
  float* sc2    = ws + off; off += DMLP;
  float* sh2    = ws + off; off += DMLP;
  // total ~13.8M float-slots ~55 MB

  k_conv_weights<<<512, 256, 0, stream>>>(Wih, Whh, bih, bhh, projW,
                                          Wihb, Whhb, projWb, bsum);
  k_embed_mfma<<<dim3(NROW/64, 5), 512, 0, stream>>>(embed, projWb, projb, s1, s2, Pb);
  k_bn_partial<<<dim3(60,2), 320, 0, stream>>>(Pb, ps, psq);
  k_bn_final<<<2, 320, 0, stream>>>(ps, psq, bn_g, bn_b, bnsc, bnsh);
  k_bn_apply<<<NROW/8, 256, 0, stream>>>(Pb, bnsc, bnsh);

  k_lstm_fused<<<32, 512, 0, stream>>>(Pb, Wihb, Whhb, bsum, Hout);

  k_dist_pool<<<BATCH, 256, 0, stream>>>(Hout, pooled);
  k_mlp1<<<BATCH, 256, 0, stream>>>(pooled, extra, W1, b1, y1);
  k_mlp_bn<<<DMLP/256, 256, 0, stream>>>(y1, g1, be1, sc1, sh1);
  k_mlp2<<<BATCH/4, 256, 0, stream>>>(y1, sc1, sh1, W2, b2, y2);
  k_mlp_bn<<<DMLP/256, 256, 0, stream>>>(y2, g2, be2, sc2, sh2);
  k_mlp3<<<BATCH, 256, 0, stream>>>(y2, sc2, sh2, W3, b3, out);
}

// Round 5
// 1007.408 us; speedup vs baseline: 8.0126x; 8.0126x over previous
//
#include <hip/hip_runtime.h>
#include <hip/hip_bf16.h>

#define S_LEN 60
#define BATCH 256
#define EMB   300
#define EMBP  320              /* padded K for proj & x-part (zero cols 300..319) */
#define HID   512
#define DMLP  1024
#define NROW  (2*S_LEN*BATCH)  /* 30720 */
#define RPS   (S_LEN*BATCH)    /* 15360 */

typedef __attribute__((ext_vector_type(8))) short short8v;
typedef __attribute__((ext_vector_type(4))) float f32x4;

static __device__ __forceinline__ float sigf(float x){
  return 1.0f/(1.0f+__expf(-x));
}
static __device__ __forceinline__ float tanh_fast(float x){
  x = fminf(fmaxf(x,-40.0f),40.0f);
  float a = __expf(2.0f*x);
  return (a-1.0f)/(a+1.0f);
}
static __device__ __forceinline__ unsigned short f2b(float v){
  __hip_bfloat16 h = __float2bfloat16(v);
  return *(unsigned short*)&h;
}
static __device__ __forceinline__ float b2f(unsigned short u){
  return __uint_as_float(((unsigned int)u)<<16);
}

// ---------------------------------------------------------------------------
// K-conv: weights -> bf16 (Wih & projW padded), bsum = bih+bhh
// ---------------------------------------------------------------------------
__global__ __launch_bounds__(256) void k_conv_weights(
    const float* __restrict__ Wih, const float* __restrict__ Whh,
    const float* __restrict__ bih, const float* __restrict__ bhh,
    const float* __restrict__ projW,
    unsigned short* __restrict__ Wihb, unsigned short* __restrict__ Whhb,
    unsigned short* __restrict__ projWb, float* __restrict__ bsum)
{
  const int tid = blockIdx.x*256 + threadIdx.x;
  const int stride = gridDim.x*256;
  for (int i=tid; i<2048*EMBP; i+=stride){
    int n = i/EMBP, k = i - n*EMBP;
    Wihb[i] = f2b((k<EMB) ? Wih[(size_t)n*EMB + k] : 0.0f);
  }
  for (int i=tid; i<2048*HID; i+=stride) Whhb[i] = f2b(Whh[i]);
  for (int i=tid; i<EMBP*EMBP; i+=stride){
    int n = i/EMBP, k = i - n*EMBP;
    projWb[i] = f2b((n<EMB && k<EMB) ? projW[(size_t)n*EMB + k] : 0.0f);
  }
  for (int i=tid; i<2048; i+=stride) bsum[i] = bih[i]+bhh[i];
}

// ---------------------------------------------------------------------------
// K1: embedding gather + projection GEMM via MFMA -> bf16 P [30720][320]
// ---------------------------------------------------------------------------
__global__ __launch_bounds__(512) void k_embed_mfma(
    const float* __restrict__ embed, const unsigned short* __restrict__ projWb,
    const float* __restrict__ projb, const int* __restrict__ s1,
    const int* __restrict__ s2, unsigned short* __restrict__ Pb)
{
  __shared__ __align__(16) unsigned short sA0[64*40];
  __shared__ __align__(16) unsigned short sA1[64*40];
  __shared__ __align__(16) unsigned short sW0[64*40];
  __shared__ __align__(16) unsigned short sW1[64*40];
  __shared__ int stok[64];
  const int m0 = blockIdx.x*64, n0 = blockIdx.y*64;
  const int tid = threadIdx.x;
  if (tid < 64){
    int r = m0 + tid;
    stok[tid] = (r < RPS) ? s1[r] : s2[r-RPS];
  }
  __syncthreads();
  const int lane = tid & 63, w = tid>>6;
  const int wr = w>>2, wc = w&3;
  const bool isA = tid < 256;
  const int srow = (tid&255)>>2, sseg = tid&3;
  const float* Arow = embed + (size_t)stok[srow]*EMB;
  const unsigned short* Wrow = projWb + (size_t)(n0+srow)*EMBP;

  const int ldst = srow*40 + sseg*8;
  const int aoff0 = (wr*32 + (lane&15))*40 + (lane>>4)*8;
  const int aoff1 = aoff0 + 16*40;
  const int woff  = (wc*16 + (lane&15))*40 + (lane>>4)*8;

  f32x4 acc0 = {0.f,0.f,0.f,0.f}, acc1 = {0.f,0.f,0.f,0.f};

  auto loadA = [&](int kk)->uint4 {
    int kb = kk*32 + sseg*8;
    unsigned short t8[8];
    if (kb+7 < EMB){
      float4 f0 = *(const float4*)(Arow + kb);
      float4 f1 = *(const float4*)(Arow + kb + 4);
      t8[0]=f2b(f0.x); t8[1]=f2b(f0.y); t8[2]=f2b(f0.z); t8[3]=f2b(f0.w);
      t8[4]=f2b(f1.x); t8[5]=f2b(f1.y); t8[6]=f2b(f1.z); t8[7]=f2b(f1.w);
    } else {
      #pragma unroll
      for (int jq=0; jq<8; jq++){
        int k = kb+jq;
        t8[jq] = f2b((k<EMB) ? Arow[k] : 0.0f);
      }
    }
    uint4 o;
    o.x = (unsigned)t8[0] | ((unsigned)t8[1]<<16);
    o.y = (unsigned)t8[2] | ((unsigned)t8[3]<<16);
    o.z = (unsigned)t8[4] | ((unsigned)t8[5]<<16);
    o.w = (unsigned)t8[6] | ((unsigned)t8[7]<<16);
    return o;
  };

  if (isA) *(uint4*)(sA0 + ldst) = loadA(0);
  else     *(uint4*)(sW0 + ldst) = *(const uint4*)(Wrow + sseg*8);
  __syncthreads();

  for (int kk=0; kk<10; kk++){
    uint4 nv;
    if (kk < 9){
      if (isA) nv = loadA(kk+1);
      else     nv = *(const uint4*)(Wrow + (kk+1)*32 + sseg*8);
    }
    const unsigned short* A = (kk&1) ? sA1 : sA0;
    const unsigned short* W = (kk&1) ? sW1 : sW0;
    short8v af0 = *(const short8v*)(A + aoff0);
    short8v af1 = *(const short8v*)(A + aoff1);
    short8v wf  = *(const short8v*)(W + woff);
    acc0 = __builtin_amdgcn_mfma_f32_16x16x32_bf16(af0, wf, acc0, 0,0,0);
    acc1 = __builtin_amdgcn_mfma_f32_16x16x32_bf16(af1, wf, acc1, 0,0,0);
    if (kk < 9){
      unsigned short* dst = ((kk&1) ? (isA?sA0:sW0) : (isA?sA1:sW1)) + ldst;
      *(uint4*)dst = nv;
    }
    __syncthreads();
  }

  const int cc = wc*16 + (lane&15);
  const int n = n0 + cc;
  const float bias = (n < EMB) ? projb[n] : 0.0f;
  const bool valid = (n < EMB);
  #pragma unroll
  for (int v=0; v<4; v++){
    int r0 = wr*32 + (lane>>4)*4 + v;
    Pb[(size_t)(m0+r0)*EMBP + n]    = f2b(valid ? acc0[v]+bias : 0.0f);
    Pb[(size_t)(m0+r0+16)*EMBP + n] = f2b(valid ? acc1[v]+bias : 0.0f);
  }
}

// ---------------------------------------------------------------------------
// K2: BN partial sums over bf16 P
// ---------------------------------------------------------------------------
__global__ __launch_bounds__(320) void k_bn_partial(const unsigned short* __restrict__ Pb,
    float* __restrict__ ps, float* __restrict__ psq)
{
  const int rb = blockIdx.x, sent = blockIdx.y, t = threadIdx.x;
  if (t >= EMB) return;
  const unsigned short* base = Pb + ((size_t)sent*RPS + (size_t)rb*256)*EMBP;
  float s=0.0f, q=0.0f;
  for (int r=0;r<256;r++){
    float v = b2f(base[(size_t)r*EMBP + t]);
    s += v; q = fmaf(v,v,q);
  }
  ps [(size_t)(sent*60+rb)*EMB + t] = s;
  psq[(size_t)(sent*60+rb)*EMB + t] = q;
}

__global__ __launch_bounds__(320) void k_bn_final(const float* __restrict__ ps,
    const float* __restrict__ psq, const float* __restrict__ g,
    const float* __restrict__ b, float* __restrict__ scale, float* __restrict__ shift)
{
  const int sent = blockIdx.x, t = threadIdx.x;
  if (t >= EMB) return;
  float s=0.0f, q=0.0f;
  for (int i=0;i<60;i++){
    s += ps [(size_t)(sent*60+i)*EMB + t];
    q += psq[(size_t)(sent*60+i)*EMB + t];
  }
  float mean = s * (1.0f/15360.0f);
  float var  = q * (1.0f/15360.0f) - mean*mean;
  float sc = g[t] * rsqrtf(var + 1e-5f);
  scale[sent*EMB+t] = sc;
  shift[sent*EMB+t] = b[t] - mean*sc;
}

__global__ __launch_bounds__(256) void k_bn_apply(unsigned short* __restrict__ Pb,
    const float* __restrict__ scale, const float* __restrict__ shift)
{
  const int r = blockIdx.x*8 + (threadIdx.x>>5);
  const int c0 = threadIdx.x & 31;
  const int sent = (r >= RPS) ? 1 : 0;
  unsigned short* row = Pb + (size_t)r*EMBP;
  for (int c=c0; c<EMB; c+=32){
    float v = b2f(row[c]);
    v = fmaf(v, scale[sent*EMB+c], shift[sent*EMB+c]);
    row[c] = f2b(v);
  }
}

// ---------------------------------------------------------------------------
// K4: one LSTM step. Block = 64 rows x (4 gates x 16 j-cols); grid (32 j, 8 row)
// so XCD = jx%8 -> each XCD's L2 keeps only 4 W-slices (425KB) hot all 60 steps.
// BK=64, 13 k-iters, 3-deep register prefetch (load c issued 2 iters before its
// ds_write -> ~500cyc L2-latency cover), fully unrolled (static reg indices).
// LDS: A dbuf 2x5120ush + W dbuf 2x5120ush = 40KB; zs f32[64][66] overlays.
// ---------------------------------------------------------------------------
__global__ __launch_bounds__(512) void k_lstm_step(
    const unsigned short* __restrict__ Pb,    // [30720][320]
    const unsigned short* __restrict__ Wihb,  // [2048][320]
    const unsigned short* __restrict__ Whhb,  // [2048][512]
    const float* __restrict__ bsum,           // [2048]
    const unsigned short* __restrict__ Hin,   // [512][512]
    unsigned short* __restrict__ Hnext,       // [512][512]
    float* __restrict__ cst,                  // [512][512] f32
    unsigned short* __restrict__ Hout,        // [2][60][256][512]
    int tstep)
{
  __shared__ __align__(16) unsigned short smem[4*5120];   // 40960 B
  // bufA[p] = smem + p*5120 ; bufW[p] = smem + 10240 + p*5120
  float* zs = (float*)smem;

  const int tid = threadIdx.x;
  const int lane = tid & 63, w = tid >> 6;
  const int wr = w >> 2, wc = w & 3;
  const int j0 = (int)blockIdx.x * 16;
  const int m0 = (int)blockIdx.y * 64;
  const int sent = m0 >> 8;
  const int brow = m0 & 255;

  // staging role: 512 thr = 2 halves x 64 rows x 4 segs (16B each)
  const int half = tid >> 8;            // which 32-k half of the 64-k chunk
  const int rs = tid & 255;
  const int srow = rs >> 2, sseg = rs & 3;
  const int kb = half*32 + sseg*8;      // col offset within chunk
  const int ldst = half*2560 + srow*40 + sseg*8;

  const unsigned short* pAx = Pb + ((size_t)((sent*S_LEN + tstep)*BATCH) + brow + srow)*EMBP + kb;
  const unsigned short* pAh = Hin + (size_t)(m0 + srow)*HID + kb;
  const int wn = (srow>>4)*HID + j0 + (srow&15);     // gate*512 + j
  const unsigned short* pWx = Wihb + (size_t)wn*EMBP + kb;
  const unsigned short* pWh = Whhb + (size_t)wn*HID  + kb;

  auto loadA = [&](int c)->uint4 {
    return (c < 5) ? *(const uint4*)(pAx + c*64) : *(const uint4*)(pAh + (c-5)*64);
  };
  auto loadW = [&](int c)->uint4 {
    return (c < 5) ? *(const uint4*)(pWx + c*64) : *(const uint4*)(pWh + (c-5)*64);
  };

  // MFMA fragment offsets (ush units, within a chunk buffer half)
  const int aoffB = (wr*32 + (lane&15))*40 + (lane>>4)*8;
  const int woffB = (wc*16 + (lane&15))*40 + (lane>>4)*8;

  f32x4 acc0 = {0.f,0.f,0.f,0.f}, acc1 = {0.f,0.f,0.f,0.f};

  // prologue: 3 chunks in flight, chunk0 -> LDS buf0
  uint4 rA[3], rW[3];
  rA[0] = loadA(0); rW[0] = loadW(0);
  rA[1] = loadA(1); rW[1] = loadW(1);
  rA[2] = loadA(2); rW[2] = loadW(2);
  *(uint4*)(smem + ldst)         = rA[0];
  *(uint4*)(smem + 10240 + ldst) = rW[0];
  __syncthreads();

  #pragma unroll
  for (int kk = 0; kk < 13; kk++){
    if (kk + 3 < 13){
      rA[(kk+3)%3] = loadA(kk+3);
      rW[(kk+3)%3] = loadW(kk+3);
    }
    const unsigned short* A = smem + (kk&1)*5120;
    const unsigned short* W = smem + 10240 + (kk&1)*5120;
    #pragma unroll
    for (int h2 = 0; h2 < 2; h2++){
      const int bh = h2*2560;
      short8v wf = *(const short8v*)(W + bh + woffB);
      short8v a0 = *(const short8v*)(A + bh + aoffB);
      short8v a1 = *(const short8v*)(A + bh + aoffB + 16*40);
      acc0 = __builtin_amdgcn_mfma_f32_16x16x32_bf16(a0, wf, acc0, 0,0,0);
      acc1 = __builtin_amdgcn_mfma_f32_16x16x32_bf16(a1, wf, acc1, 0,0,0);
    }
    if (kk + 1 < 13){
      *(uint4*)(smem + ((kk+1)&1)*5120 + ldst)         = rA[(kk+1)%3];
      *(uint4*)(smem + 10240 + ((kk+1)&1)*5120 + ldst) = rW[(kk+1)%3];
    }
    __syncthreads();
  }

  // epilogue: z -> LDS f32 [64][66] (overlays chunk bufs, post-barrier)
  #pragma unroll
  for (int v = 0; v < 4; v++){
    int r0 = wr*32 + (lane>>4)*4 + v;
    int cc = wc*16 + (lane&15);
    zs[r0*66 + cc]      = acc0[v];
    zs[(r0+16)*66 + cc] = acc1[v];
  }
  __syncthreads();

  // cell update: 2 cells/thread (rows row_e, row_e+32), c-state in global f32
  const int row_e = tid >> 4, jj = tid & 15, j = j0 + jj;
  const float zb0 = bsum[0*HID+j], zb1 = bsum[1*HID+j];
  const float zb2 = bsum[2*HID+j], zb3 = bsum[3*HID+j];
  #pragma unroll
  for (int q = 0; q < 2; q++){
    int row = row_e + q*32;
    int r = m0 + row;
    float zi = zs[row*66 + jj]    + zb0;
    float zf = zs[row*66 + 16+jj] + zb1;
    float zg = zs[row*66 + 32+jj] + zb2;
    float zo = zs[row*66 + 48+jj] + zb3;
    size_t ci = (size_t)r*HID + j;
    float cn = fmaf(sigf(zf), cst[ci], sigf(zi)*tanh_fast(zg));
    cst[ci] = cn;
    float hn = sigf(zo)*tanh_fast(cn);
    unsigned short hb = f2b(hn);
    Hnext[ci] = hb;
    Hout[((size_t)((sent*S_LEN + tstep)*BATCH) + (r&255))*HID + j] = hb;
  }
}

// ---------------------------------------------------------------------------
// K5: fused pairwise-L2-distance + 15x15 min-pool
// ---------------------------------------------------------------------------
#define SDU 258
__global__ __launch_bounds__(256) void k_dist_pool(
    const unsigned short* __restrict__ Hout, float* __restrict__ pooled)
{
  __shared__ unsigned int h1s[S_LEN*SDU];
  __shared__ unsigned int h2s[S_LEN*SDU];
  __shared__ float n1s[S_LEN], n2s[S_LEN];
  const int b = blockIdx.x, tid = threadIdx.x;
  const unsigned int* H = (const unsigned int*)Hout;
  for (int e=tid; e<S_LEN*256; e+=256){
    int row = e>>8, cu = e&255;
    h1s[row*SDU+cu] = H[((size_t)(0*S_LEN+row)*BATCH + b)*256 + cu];
    h2s[row*SDU+cu] = H[((size_t)(1*S_LEN+row)*BATCH + b)*256 + cu];
  }
  __syncthreads();
  if (tid < S_LEN){
    const unsigned int* rp = &h1s[tid*SDU];
    float q=0.0f;
    for (int cu=0;cu<256;cu++){
      unsigned int u = rp[cu];
      float lo = __uint_as_float(u<<16);
      float hi = __uint_as_float(u & 0xffff0000u);
      q = fmaf(lo,lo,q); q = fmaf(hi,hi,q);
    }
    n1s[tid] = q;
  } else if (tid >= 64 && tid < 64+S_LEN){
    const unsigned int* rp = &h2s[(tid-64)*SDU];
    float q=0.0f;
    for (int cu=0;cu<256;cu++){
      unsigned int u = rp[cu];
      float lo = __uint_as_float(u<<16);
      float hi = __uint_as_float(u & 0xffff0000u);
      q = fmaf(lo,lo,q); q = fmaf(hi,hi,q);
    }
    n2s[tid-64] = q;
  }
  __syncthreads();
  if (tid < 225){
    const int gi = tid/15, gj = tid%15;
    float acc[4][4];
    #pragma unroll
    for (int a=0;a<4;a++)
      #pragma unroll
      for (int c=0;c<4;c++) acc[a][c]=0.0f;
    const unsigned int* r1[4]; const unsigned int* r2[4];
    #pragma unroll
    for (int a=0;a<4;a++){ r1[a]=&h1s[(gi*4+a)*SDU]; r2[a]=&h2s[(gj*4+a)*SDU]; }
    for (int cu=0;cu<256;cu++){
      float lo1[4],hi1[4],lo2[4],hi2[4];
      #pragma unroll
      for (int a=0;a<4;a++){
        unsigned int u = r1[a][cu];
        lo1[a]=__uint_as_float(u<<16); hi1[a]=__uint_as_float(u&0xffff0000u);
      }
      #pragma unroll
      for (int c=0;c<4;c++){
        unsigned int u = r2[c][cu];
        lo2[c]=__uint_as_float(u<<16); hi2[c]=__uint_as_float(u&0xffff0000u);
      }
      #pragma unroll
      for (int a=0;a<4;a++)
        #pragma unroll
        for (int c=0;c<4;c++)
          acc[a][c] = fmaf(lo1[a],lo2[c], fmaf(hi1[a],hi2[c], acc[a][c]));
    }
    float mn = 3.4e38f;
    #pragma unroll
    for (int a=0;a<4;a++)
      #pragma unroll
      for (int c=0;c<4;c++){
        float sq = n1s[gi*4+a] + n2s[gj*4+c] - 2.0f*acc[a][c];
        mn = fminf(mn, sqrtf(fmaxf(sq,0.0f)+1e-12f));
      }
    pooled[(size_t)b*225 + tid] = mn;
  }
}

// ---------------------------------------------------------------------------
// MLP kernels
// ---------------------------------------------------------------------------
__global__ __launch_bounds__(256) void k_mlp1(const float* __restrict__ pooled,
    const float* __restrict__ extra, const float* __restrict__ W1,
    const float* __restrict__ b1, float* __restrict__ y1)
{
  __shared__ __align__(16) float xs[232];
  const int b = blockIdx.x, tid = threadIdx.x;
  if (tid < 225) xs[tid] = pooled[(size_t)b*225 + tid];
  else if (tid < 232) xs[tid] = extra[(size_t)b*7 + (tid-225)];
  __syncthreads();
  #pragma unroll
  for (int q=0;q<4;q++){
    int n = tid + q*256;
    float acc = b1[n];
    const float4* wr = (const float4*)(W1 + (size_t)n*232);
    const float4* xr = (const float4*)xs;
    for (int k4=0;k4<58;k4++){
      float4 w = wr[k4]; float4 x = xr[k4];
      acc = fmaf(w.x,x.x, fmaf(w.y,x.y, fmaf(w.z,x.z, fmaf(w.w,x.w, acc))));
    }
    y1[(size_t)b*DMLP + n] = fmaxf(acc, 0.0f);
  }
}

__global__ __launch_bounds__(256) void k_mlp_bn(const float* __restrict__ y,
    const float* __restrict__ g, const float* __restrict__ be,
    float* __restrict__ scale, float* __restrict__ shift)
{
  const int n = blockIdx.x*256 + threadIdx.x;
  float s=0.0f, q=0.0f;
  for (int b=0;b<BATCH;b++){
    float v = y[(size_t)b*DMLP + n];
    s += v; q = fmaf(v,v,q);
  }
  float mean = s * (1.0f/256.0f);
  float var  = q * (1.0f/256.0f) - mean*mean;
  float sc = g[n] * rsqrtf(var + 1e-5f);
  scale[n] = sc;
  shift[n] = be[n] - mean*sc;
}

__global__ __launch_bounds__(256) void k_mlp2(const float* __restrict__ y1,
    const float* __restrict__ scale1, const float* __restrict__ shift1,
    const float* __restrict__ W2, const float* __restrict__ b2,
    float* __restrict__ y2)
{
  __shared__ __align__(16) float xs[4][DMLP];
  const int b0 = blockIdx.x*4, tid = threadIdx.x;
  for (int e=tid; e<4*DMLP; e+=256){
    int bb = e>>10, k = e&1023;
    xs[bb][k] = fmaf(y1[(size_t)(b0+bb)*DMLP + k], scale1[k], shift1[k]);
  }
  __syncthreads();
  #pragma unroll
  for (int q=0;q<4;q++){
    int n = tid + q*256;
    float a0=0.0f,a1=0.0f,a2=0.0f,a3=0.0f;
    const float4* wr = (const float4*)(W2 + (size_t)n*DMLP);
    for (int k4=0;k4<256;k4++){
      float4 w = wr[k4];
      float4 x0 = ((const float4*)xs[0])[k4];
      float4 x1 = ((const float4*)xs[1])[k4];
      float4 x2 = ((const float4*)xs[2])[k4];
      float4 x3 = ((const float4*)xs[3])[k4];
      a0 = fmaf(w.x,x0.x, fmaf(w.y,x0.y, fmaf(w.z,x0.z, fmaf(w.w,x0.w, a0))));
      a1 = fmaf(w.x,x1.x, fmaf(w.y,x1.y, fmaf(w.z,x1.z, fmaf(w.w,x1.w, a1))));
      a2 = fmaf(w.x,x2.x, fmaf(w.y,x2.y, fmaf(w.z,x2.z, fmaf(w.w,x2.w, a2))));
      a3 = fmaf(w.x,x3.x, fmaf(w.y,x3.y, fmaf(w.z,x3.z, fmaf(w.w,x3.w, a3))));
    }
    float bias = b2[n];
    y2[(size_t)(b0+0)*DMLP + n] = fmaxf(a0+bias, 0.0f);
    y2[(size_t)(b0+1)*DMLP + n] = fmaxf(a1+bias, 0.0f);
    y2[(size_t)(b0+2)*DMLP + n] = fmaxf(a2+bias, 0.0f);
    y2[(size_t)(b0+3)*DMLP + n] = fmaxf(a3+bias, 0.0f);
  }
}

__global__ __launch_bounds__(256) void k_mlp3(const float* __restrict__ y2,
    const float* __restrict__ scale2, const float* __restrict__ shift2,
    const float* __restrict__ W3, const float* __restrict__ b3,
    float* __restrict__ out)
{
  __shared__ float r0[256], r1[256];
  const int b = blockIdx.x, tid = threadIdx.x;
  float p0=0.0f, p1=0.0f;
  #pragma unroll
  for (int q=0;q<4;q++){
    int k = tid + q*256;
    float x = fmaf(y2[(size_t)b*DMLP + k], scale2[k], shift2[k]);
    p0 = fmaf(x, W3[k], p0);
    p1 = fmaf(x, W3[DMLP+k], p1);
  }
  r0[tid]=p0; r1[tid]=p1;
  __syncthreads();
  for (int s=128; s>0; s>>=1){
    if (tid<s){ r0[tid]+=r0[tid+s]; r1[tid]+=r1[tid+s]; }
    __syncthreads();
  }
  if (tid==0){
    float l0 = r0[0]+b3[0], l1 = r1[0]+b3[1];
    float m = fmaxf(l0,l1);
    float lse = m + logf(__expf(l0-m)+__expf(l1-m));
    out[b*2+0] = l0-lse;
    out[b*2+1] = l1-lse;
  }
}

// ---------------------------------------------------------------------------
extern "C" void kernel_launch(void* const* d_in, const int* in_sizes, int n_in,
                              void* d_out, int out_size, void* d_ws, size_t ws_size,
                              hipStream_t stream)
{
  (void)in_sizes; (void)n_in; (void)out_size; (void)ws_size;
  const float* embed = (const float*)d_in[0];
  const float* projW = (const float*)d_in[1];
  const float* projb = (const float*)d_in[2];
  const float* bn_g  = (const float*)d_in[3];
  const float* bn_b  = (const float*)d_in[4];
  const float* Wih   = (const float*)d_in[5];
  const float* Whh   = (const float*)d_in[6];
  const float* bih   = (const float*)d_in[7];
  const float* bhh   = (const float*)d_in[8];
  const float* W1    = (const float*)d_in[9];
  const float* b1    = (const float*)d_in[10];
  const float* g1    = (const float*)d_in[11];
  const float* be1   = (const float*)d_in[12];
  const float* W2    = (const float*)d_in[13];
  const float* b2    = (const float*)d_in[14];
  const float* g2    = (const float*)d_in[15];
  const float* be2   = (const float*)d_in[16];
  const float* W3    = (const float*)d_in[17];
  const float* b3    = (const float*)d_in[18];
  const float* extra = (const float*)d_in[19];
  const int*   s1    = (const int*)d_in[20];
  const int*   s2    = (const int*)d_in[21];
  float* out = (float*)d_out;

  float* ws = (float*)d_ws;
  size_t off = 0;
  float* ps   = ws + off; off += (size_t)2*60*EMB;
  float* psq  = ws + off; off += (size_t)2*60*EMB;
  float* bnsc = ws + off; off += 2*EMB;
  float* bnsh = ws + off; off += 2*EMB;
  float* bsum = ws + off; off += 2048;
  unsigned short* Pb     = (unsigned short*)(ws + off); off += (size_t)NROW*EMBP/2;
  unsigned short* Wihb   = (unsigned short*)(ws + off); off += (size_t)2048*EMBP/2;
  unsigned short* Whhb   = (unsigned short*)(ws + off); off += (size_t)2048*HID/2;
  unsigned short* projWb = (unsigned short*)(ws + off); off += (size_t)EMBP*EMBP/2;
  float* cst = ws + off; off += (size_t)512*HID;           // f32 c-state
  unsigned short* Hb0 = (unsigned short*)(ws + off); off += (size_t)512*HID/2;
  unsigned short* Hb1 = (unsigned short*)(ws + off); off += (size_t)512*HID/2;
  unsigned short* Hout = (unsigned short*)(ws + off); off += (size_t)2*S_LEN*BATCH*HID/2;
  float* pooled = ws + off; off += (size_t)BATCH*225;
  float* y1     = ws + off; off += (size_t)BATCH*DMLP;
  float* y2     = ws + off; off += (size_t)BATCH*DMLP;
  float* sc1    = ws + off; off += DMLP;
  float* sh1    = ws + off; off += DMLP;
  float* sc2    = ws + off; off += DMLP;
  float* sh2    = ws + off; off += DMLP;
  // total ~14.1M float-slots ~57 MB

  // zero c-state (f32) + Hb0 (bf16), contiguous
  hipMemsetAsync(cst, 0, (size_t)(512*HID)*sizeof(float) + (size_t)(512*HID)*sizeof(unsigned short), stream);

  k_conv_weights<<<512, 256, 0, stream>>>(Wih, Whh, bih, bhh, projW,
                                          Wihb, Whhb, projWb, bsum);
  k_embed_mfma<<<dim3(NROW/64, 5), 512, 0, stream>>>(embed, projWb, projb, s1, s2, Pb);
  k_bn_partial<<<dim3(60,2), 320, 0, stream>>>(Pb, ps, psq);
  k_bn_final<<<2, 320, 0, stream>>>(ps, psq, bn_g, bn_b, bnsc, bnsh);
  k_bn_apply<<<NROW/8, 256, 0, stream>>>(Pb, bnsc, bnsh);

  for (int t=0; t<S_LEN; t++){
    const unsigned short* hin = (t & 1) ? Hb1 : Hb0;
    unsigned short*      hnxt = (t & 1) ? Hb0 : Hb1;
    k_lstm_step<<<dim3(32,8), 512, 0, stream>>>(Pb, Wihb, Whhb, bsum,
                                                hin, hnxt, cst, Hout, t);
  }

  k_dist_pool<<<BATCH, 256, 0, stream>>>(Hout, pooled);
  k_mlp1<<<BATCH, 256, 0, stream>>>(pooled, extra, W1, b1, y1);
  k_mlp_bn<<<DMLP/256, 256, 0, stream>>>(y1, g1, be1, sc1, sh1);
  k_mlp2<<<BATCH/4, 256, 0, stream>>>(y1, sc1, sh1, W2, b2, y2);
  k_mlp_bn<<<DMLP/256, 256, 0, stream>>>(y2, g2, be2, sc2, sh2);
  k_mlp3<<<BATCH, 256, 0, stream>>>(y2, sc2, sh2, W3, b3, out);
}

// Round 7
// 879.001 us; speedup vs baseline: 9.1831x; 1.1461x over previous
//
#include <hip/hip_runtime.h>
#include <hip/hip_bf16.h>

#define S_LEN 60
#define BATCH 256
#define EMB   300
#define EMBP  320              /* padded K for proj & x-part (zero cols 300..319) */
#define HID   512
#define DMLP  1024
#define NROW  (2*S_LEN*BATCH)  /* 30720 */
#define RPS   (S_LEN*BATCH)    /* 15360 */

typedef __attribute__((ext_vector_type(8))) short short8v;
typedef __attribute__((ext_vector_type(4))) float f32x4;

static __device__ __forceinline__ float sigf(float x){
  return 1.0f/(1.0f+__expf(-x));
}
static __device__ __forceinline__ float tanh_fast(float x){
  x = fminf(fmaxf(x,-40.0f),40.0f);
  float a = __expf(2.0f*x);
  return (a-1.0f)/(a+1.0f);
}
static __device__ __forceinline__ unsigned short f2b(float v){
  __hip_bfloat16 h = __float2bfloat16(v);
  return *(unsigned short*)&h;
}
static __device__ __forceinline__ float b2f(unsigned short u){
  return __uint_as_float(((unsigned int)u)<<16);
}

// ---------------------------------------------------------------------------
// K-conv: weights -> bf16 (Wih & projW padded), bsum = bih+bhh
// ---------------------------------------------------------------------------
__global__ __launch_bounds__(256) void k_conv_weights(
    const float* __restrict__ Wih, const float* __restrict__ Whh,
    const float* __restrict__ bih, const float* __restrict__ bhh,
    const float* __restrict__ projW,
    unsigned short* __restrict__ Wihb, unsigned short* __restrict__ Whhb,
    unsigned short* __restrict__ projWb, float* __restrict__ bsum)
{
  const int tid = blockIdx.x*256 + threadIdx.x;
  const int stride = gridDim.x*256;
  for (int i=tid; i<2048*EMBP; i+=stride){
    int n = i/EMBP, k = i - n*EMBP;
    Wihb[i] = f2b((k<EMB) ? Wih[(size_t)n*EMB + k] : 0.0f);
  }
  for (int i=tid; i<2048*HID; i+=stride) Whhb[i] = f2b(Whh[i]);
  for (int i=tid; i<EMBP*EMBP; i+=stride){
    int n = i/EMBP, k = i - n*EMBP;
    projWb[i] = f2b((n<EMB && k<EMB) ? projW[(size_t)n*EMB + k] : 0.0f);
  }
  for (int i=tid; i<2048; i+=stride) bsum[i] = bih[i]+bhh[i];
}

// ---------------------------------------------------------------------------
// K1: embedding gather + projection GEMM via MFMA -> bf16 P [30720][320]
// ---------------------------------------------------------------------------
__global__ __launch_bounds__(512) void k_embed_mfma(
    const float* __restrict__ embed, const unsigned short* __restrict__ projWb,
    const float* __restrict__ projb, const int* __restrict__ s1,
    const int* __restrict__ s2, unsigned short* __restrict__ Pb)
{
  __shared__ __align__(16) unsigned short sA0[64*40];
  __shared__ __align__(16) unsigned short sA1[64*40];
  __shared__ __align__(16) unsigned short sW0[64*40];
  __shared__ __align__(16) unsigned short sW1[64*40];
  __shared__ int stok[64];
  const int m0 = blockIdx.x*64, n0 = blockIdx.y*64;
  const int tid = threadIdx.x;
  if (tid < 64){
    int r = m0 + tid;
    stok[tid] = (r < RPS) ? s1[r] : s2[r-RPS];
  }
  __syncthreads();
  const int lane = tid & 63, w = tid>>6;
  const int wr = w>>2, wc = w&3;
  const bool isA = tid < 256;
  const int srow = (tid&255)>>2, sseg = tid&3;
  const float* Arow = embed + (size_t)stok[srow]*EMB;
  const unsigned short* Wrow = projWb + (size_t)(n0+srow)*EMBP;

  const int ldst = srow*40 + sseg*8;
  const int aoff0 = (wr*32 + (lane&15))*40 + (lane>>4)*8;
  const int aoff1 = aoff0 + 16*40;
  const int woff  = (wc*16 + (lane&15))*40 + (lane>>4)*8;

  f32x4 acc0 = {0.f,0.f,0.f,0.f}, acc1 = {0.f,0.f,0.f,0.f};

  auto loadA = [&](int kk)->uint4 {
    int kb = kk*32 + sseg*8;
    unsigned short t8[8];
    if (kb+7 < EMB){
      float4 f0 = *(const float4*)(Arow + kb);
      float4 f1 = *(const float4*)(Arow + kb + 4);
      t8[0]=f2b(f0.x); t8[1]=f2b(f0.y); t8[2]=f2b(f0.z); t8[3]=f2b(f0.w);
      t8[4]=f2b(f1.x); t8[5]=f2b(f1.y); t8[6]=f2b(f1.z); t8[7]=f2b(f1.w);
    } else {
      #pragma unroll
      for (int jq=0; jq<8; jq++){
        int k = kb+jq;
        t8[jq] = f2b((k<EMB) ? Arow[k] : 0.0f);
      }
    }
    uint4 o;
    o.x = (unsigned)t8[0] | ((unsigned)t8[1]<<16);
    o.y = (unsigned)t8[2] | ((unsigned)t8[3]<<16);
    o.z = (unsigned)t8[4] | ((unsigned)t8[5]<<16);
    o.w = (unsigned)t8[6] | ((unsigned)t8[7]<<16);
    return o;
  };

  if (isA) *(uint4*)(sA0 + ldst) = loadA(0);
  else     *(uint4*)(sW0 + ldst) = *(const uint4*)(Wrow + sseg*8);
  __syncthreads();

  for (int kk=0; kk<10; kk++){
    uint4 nv;
    if (kk < 9){
      if (isA) nv = loadA(kk+1);
      else     nv = *(const uint4*)(Wrow + (kk+1)*32 + sseg*8);
    }
    const unsigned short* A = (kk&1) ? sA1 : sA0;
    const unsigned short* W = (kk&1) ? sW1 : sW0;
    short8v af0 = *(const short8v*)(A + aoff0);
    short8v af1 = *(const short8v*)(A + aoff1);
    short8v wf  = *(const short8v*)(W + woff);
    acc0 = __builtin_amdgcn_mfma_f32_16x16x32_bf16(af0, wf, acc0, 0,0,0);
    acc1 = __builtin_amdgcn_mfma_f32_16x16x32_bf16(af1, wf, acc1, 0,0,0);
    if (kk < 9){
      unsigned short* dst = ((kk&1) ? (isA?sA0:sW0) : (isA?sA1:sW1)) + ldst;
      *(uint4*)dst = nv;
    }
    __syncthreads();
  }

  const int cc = wc*16 + (lane&15);
  const int n = n0 + cc;
  const float bias = (n < EMB) ? projb[n] : 0.0f;
  const bool valid = (n < EMB);
  #pragma unroll
  for (int v=0; v<4; v++){
    int r0 = wr*32 + (lane>>4)*4 + v;
    Pb[(size_t)(m0+r0)*EMBP + n]    = f2b(valid ? acc0[v]+bias : 0.0f);
    Pb[(size_t)(m0+r0+16)*EMBP + n] = f2b(valid ? acc1[v]+bias : 0.0f);
  }
}

// ---------------------------------------------------------------------------
// K2: BN partial sums over bf16 P
// ---------------------------------------------------------------------------
__global__ __launch_bounds__(320) void k_bn_partial(const unsigned short* __restrict__ Pb,
    float* __restrict__ ps, float* __restrict__ psq)
{
  const int rb = blockIdx.x, sent = blockIdx.y, t = threadIdx.x;
  if (t >= EMB) return;
  const unsigned short* base = Pb + ((size_t)sent*RPS + (size_t)rb*256)*EMBP;
  float s=0.0f, q=0.0f;
  for (int r=0;r<256;r++){
    float v = b2f(base[(size_t)r*EMBP + t]);
    s += v; q = fmaf(v,v,q);
  }
  ps [(size_t)(sent*60+rb)*EMB + t] = s;
  psq[(size_t)(sent*60+rb)*EMB + t] = q;
}

__global__ __launch_bounds__(320) void k_bn_final(const float* __restrict__ ps,
    const float* __restrict__ psq, const float* __restrict__ g,
    const float* __restrict__ b, float* __restrict__ scale, float* __restrict__ shift)
{
  const int sent = blockIdx.x, t = threadIdx.x;
  if (t >= EMB) return;
  float s=0.0f, q=0.0f;
  for (int i=0;i<60;i++){
    s += ps [(size_t)(sent*60+i)*EMB + t];
    q += psq[(size_t)(sent*60+i)*EMB + t];
  }
  float mean = s * (1.0f/15360.0f);
  float var  = q * (1.0f/15360.0f) - mean*mean;
  float sc = g[t] * rsqrtf(var + 1e-5f);
  scale[sent*EMB+t] = sc;
  shift[sent*EMB+t] = b[t] - mean*sc;
}

__global__ __launch_bounds__(256) void k_bn_apply(unsigned short* __restrict__ Pb,
    const float* __restrict__ scale, const float* __restrict__ shift)
{
  const int r = blockIdx.x*8 + (threadIdx.x>>5);
  const int c0 = threadIdx.x & 31;
  const int sent = (r >= RPS) ? 1 : 0;
  unsigned short* row = Pb + (size_t)r*EMBP;
  for (int c=c0; c<EMB; c+=32){
    float v = b2f(row[c]);
    v = fmaf(v, scale[sent*EMB+c], shift[sent*EMB+c]);
    row[c] = f2b(v);
  }
}

// ---------------------------------------------------------------------------
// K4: one LSTM step (proven R5 structure)
// ---------------------------------------------------------------------------
__global__ __launch_bounds__(512) void k_lstm_step(
    const unsigned short* __restrict__ Pb,
    const unsigned short* __restrict__ Wihb,
    const unsigned short* __restrict__ Whhb,
    const float* __restrict__ bsum,
    const unsigned short* __restrict__ Hin,
    unsigned short* __restrict__ Hnext,
    float* __restrict__ cst,
    unsigned short* __restrict__ Hout,
    int tstep)
{
  __shared__ __align__(16) unsigned short smem[4*5120];   // 40960 B
  float* zs = (float*)smem;

  const int tid = threadIdx.x;
  const int lane = tid & 63, w = tid >> 6;
  const int wr = w >> 2, wc = w & 3;
  const int j0 = (int)blockIdx.x * 16;
  const int m0 = (int)blockIdx.y * 64;
  const int sent = m0 >> 8;
  const int brow = m0 & 255;

  const int half = tid >> 8;
  const int rs = tid & 255;
  const int srow = rs >> 2, sseg = rs & 3;
  const int kb = half*32 + sseg*8;
  const int ldst = half*2560 + srow*40 + sseg*8;

  const unsigned short* pAx = Pb + ((size_t)((sent*S_LEN + tstep)*BATCH) + brow + srow)*EMBP + kb;
  const unsigned short* pAh = Hin + (size_t)(m0 + srow)*HID + kb;
  const int wn = (srow>>4)*HID + j0 + (srow&15);
  const unsigned short* pWx = Wihb + (size_t)wn*EMBP + kb;
  const unsigned short* pWh = Whhb + (size_t)wn*HID  + kb;

  auto loadA = [&](int c)->uint4 {
    return (c < 5) ? *(const uint4*)(pAx + c*64) : *(const uint4*)(pAh + (c-5)*64);
  };
  auto loadW = [&](int c)->uint4 {
    return (c < 5) ? *(const uint4*)(pWx + c*64) : *(const uint4*)(pWh + (c-5)*64);
  };

  const int aoffB = (wr*32 + (lane&15))*40 + (lane>>4)*8;
  const int woffB = (wc*16 + (lane&15))*40 + (lane>>4)*8;

  f32x4 acc0 = {0.f,0.f,0.f,0.f}, acc1 = {0.f,0.f,0.f,0.f};

  uint4 rA[3], rW[3];
  rA[0] = loadA(0); rW[0] = loadW(0);
  rA[1] = loadA(1); rW[1] = loadW(1);
  rA[2] = loadA(2); rW[2] = loadW(2);
  *(uint4*)(smem + ldst)         = rA[0];
  *(uint4*)(smem + 10240 + ldst) = rW[0];
  __syncthreads();

  #pragma unroll
  for (int kk = 0; kk < 13; kk++){
    if (kk + 3 < 13){
      rA[(kk+3)%3] = loadA(kk+3);
      rW[(kk+3)%3] = loadW(kk+3);
    }
    const unsigned short* A = smem + (kk&1)*5120;
    const unsigned short* W = smem + 10240 + (kk&1)*5120;
    #pragma unroll
    for (int h2 = 0; h2 < 2; h2++){
      const int bh = h2*2560;
      short8v wf = *(const short8v*)(W + bh + woffB);
      short8v a0 = *(const short8v*)(A + bh + aoffB);
      short8v a1 = *(const short8v*)(A + bh + aoffB + 16*40);
      acc0 = __builtin_amdgcn_mfma_f32_16x16x32_bf16(a0, wf, acc0, 0,0,0);
      acc1 = __builtin_amdgcn_mfma_f32_16x16x32_bf16(a1, wf, acc1, 0,0,0);
    }
    if (kk + 1 < 13){
      *(uint4*)(smem + ((kk+1)&1)*5120 + ldst)         = rA[(kk+1)%3];
      *(uint4*)(smem + 10240 + ((kk+1)&1)*5120 + ldst) = rW[(kk+1)%3];
    }
    __syncthreads();
  }

  #pragma unroll
  for (int v = 0; v < 4; v++){
    int r0 = wr*32 + (lane>>4)*4 + v;
    int cc = wc*16 + (lane&15);
    zs[r0*66 + cc]      = acc0[v];
    zs[(r0+16)*66 + cc] = acc1[v];
  }
  __syncthreads();

  const int row_e = tid >> 4, jj = tid & 15, j = j0 + jj;
  const float zb0 = bsum[0*HID+j], zb1 = bsum[1*HID+j];
  const float zb2 = bsum[2*HID+j], zb3 = bsum[3*HID+j];
  #pragma unroll
  for (int q = 0; q < 2; q++){
    int row = row_e + q*32;
    int r = m0 + row;
    float zi = zs[row*66 + jj]    + zb0;
    float zf = zs[row*66 + 16+jj] + zb1;
    float zg = zs[row*66 + 32+jj] + zb2;
    float zo = zs[row*66 + 48+jj] + zb3;
    size_t ci = (size_t)r*HID + j;
    float cn = fmaf(sigf(zf), cst[ci], sigf(zi)*tanh_fast(zg));
    cst[ci] = cn;
    float hn = sigf(zo)*tanh_fast(cn);
    unsigned short hb = f2b(hn);
    Hnext[ci] = hb;
    Hout[((size_t)((sent*S_LEN + tstep)*BATCH) + (r&255))*HID + j] = hb;
  }
}

// ---------------------------------------------------------------------------
// K5: fused pairwise-L2-distance + 15x15 min-pool
// ---------------------------------------------------------------------------
#define SDU 258
__global__ __launch_bounds__(256) void k_dist_pool(
    const unsigned short* __restrict__ Hout, float* __restrict__ pooled)
{
  __shared__ unsigned int h1s[S_LEN*SDU];
  __shared__ unsigned int h2s[S_LEN*SDU];
  __shared__ float n1s[S_LEN], n2s[S_LEN];
  const int b = blockIdx.x, tid = threadIdx.x;
  const unsigned int* H = (const unsigned int*)Hout;
  for (int e=tid; e<S_LEN*256; e+=256){
    int row = e>>8, cu = e&255;
    h1s[row*SDU+cu] = H[((size_t)(0*S_LEN+row)*BATCH + b)*256 + cu];
    h2s[row*SDU+cu] = H[((size_t)(1*S_LEN+row)*BATCH + b)*256 + cu];
  }
  __syncthreads();
  if (tid < S_LEN){
    const unsigned int* rp = &h1s[tid*SDU];
    float q=0.0f;
    for (int cu=0;cu<256;cu++){
      unsigned int u = rp[cu];
      float lo = __uint_as_float(u<<16);
      float hi = __uint_as_float(u & 0xffff0000u);
      q = fmaf(lo,lo,q); q = fmaf(hi,hi,q);
    }
    n1s[tid] = q;
  } else if (tid >= 64 && tid < 64+S_LEN){
    const unsigned int* rp = &h2s[(tid-64)*SDU];
    float q=0.0f;
    for (int cu=0;cu<256;cu++){
      unsigned int u = rp[cu];
      float lo = __uint_as_float(u<<16);
      float hi = __uint_as_float(u & 0xffff0000u);
      q = fmaf(lo,lo,q); q = fmaf(hi,hi,q);
    }
    n2s[tid-64] = q;
  }
  __syncthreads();
  if (tid < 225){
    const int gi = tid/15, gj = tid%15;
    float acc[4][4];
    #pragma unroll
    for (int a=0;a<4;a++)
      #pragma unroll
      for (int c=0;c<4;c++) acc[a][c]=0.0f;
    const unsigned int* r1[4]; const unsigned int* r2[4];
    #pragma unroll
    for (int a=0;a<4;a++){ r1[a]=&h1s[(gi*4+a)*SDU]; r2[a]=&h2s[(gj*4+a)*SDU]; }
    for (int cu=0;cu<256;cu++){
      float lo1[4],hi1[4],lo2[4],hi2[4];
      #pragma unroll
      for (int a=0;a<4;a++){
        unsigned int u = r1[a][cu];
        lo1[a]=__uint_as_float(u<<16); hi1[a]=__uint_as_float(u&0xffff0000u);
      }
      #pragma unroll
      for (int c=0;c<4;c++){
        unsigned int u = r2[c][cu];
        lo2[c]=__uint_as_float(u<<16); hi2[c]=__uint_as_float(u&0xffff0000u);
      }
      #pragma unroll
      for (int a=0;a<4;a++)
        #pragma unroll
        for (int c=0;c<4;c++)
          acc[a][c] = fmaf(lo1[a],lo2[c], fmaf(hi1[a],hi2[c], acc[a][c]));
    }
    float mn = 3.4e38f;
    #pragma unroll
    for (int a=0;a<4;a++)
      #pragma unroll
      for (int c=0;c<4;c++){
        float sq = n1s[gi*4+a] + n2s[gj*4+c] - 2.0f*acc[a][c];
        mn = fminf(mn, sqrtf(fmaxf(sq,0.0f)+1e-12f));
      }
    pooled[(size_t)b*225 + tid] = mn;
  }
}

// ---------------------------------------------------------------------------
// MLP kernels — fp32 math (R5-identical numerics), restructured parallelism
// ---------------------------------------------------------------------------
__global__ __launch_bounds__(256) void k_mlp1(const float* __restrict__ pooled,
    const float* __restrict__ extra, const float* __restrict__ W1,
    const float* __restrict__ b1, float* __restrict__ y1)
{
  __shared__ __align__(16) float xs[232];
  const int b = blockIdx.x, tid = threadIdx.x;
  if (tid < 225) xs[tid] = pooled[(size_t)b*225 + tid];
  else if (tid < 232) xs[tid] = extra[(size_t)b*7 + (tid-225)];
  __syncthreads();
  #pragma unroll
  for (int q=0;q<4;q++){
    int n = tid + q*256;
    float acc = b1[n];
    const float4* wr = (const float4*)(W1 + (size_t)n*232);
    const float4* xr = (const float4*)xs;
    for (int k4=0;k4<58;k4++){
      float4 w = wr[k4]; float4 x = xr[k4];
      acc = fmaf(w.x,x.x, fmaf(w.y,x.y, fmaf(w.z,x.z, fmaf(w.w,x.w, acc))));
    }
    y1[(size_t)b*DMLP + n] = fmaxf(acc, 0.0f);
  }
}

// BN stats over batch: 16 blocks x 256 thr; block owns 64 channels, 4 row-groups
__global__ __launch_bounds__(256) void k_mlp_bn2(const float* __restrict__ y,
    const float* __restrict__ g, const float* __restrict__ be,
    float* __restrict__ scale, float* __restrict__ shift)
{
  __shared__ float sred[256], qred[256];
  const int c0 = blockIdx.x*64;
  const int ch = threadIdx.x & 63, grp = threadIdx.x >> 6;
  const int n = c0 + ch;
  float s=0.0f, q=0.0f;
  for (int b=grp*64; b<grp*64+64; b++){
    float v = y[(size_t)b*DMLP + n];
    s += v; q = fmaf(v,v,q);
  }
  sred[threadIdx.x]=s; qred[threadIdx.x]=q;
  __syncthreads();
  if (grp==0){
    s = sred[ch] + sred[64+ch] + sred[128+ch] + sred[192+ch];
    q = qred[ch] + qred[64+ch] + qred[128+ch] + qred[192+ch];
    float mean = s * (1.0f/256.0f);
    float var  = q * (1.0f/256.0f) - mean*mean;
    float sc = g[n] * rsqrtf(var + 1e-5f);
    scale[n] = sc;
    shift[n] = be[n] - mean*sc;
  }
}

// MLP2 GEMM fp32, split-K x4: grid (16 nt, 4 mt, 4 kc), 256 thr, 64x64 tile
__global__ __launch_bounds__(256) void k_mlp2_gemm(
    const float* __restrict__ y1, const float* __restrict__ scale1,
    const float* __restrict__ shift1, const float* __restrict__ W2,
    float* __restrict__ y2part)
{
  __shared__ float As[64][33];
  __shared__ float Bs[64][33];
  const int n0 = blockIdx.x*64, m0 = blockIdx.y*64;
  const int kbase = blockIdx.z*256;
  const int tid = threadIdx.x;
  const int tx = tid & 15, ty = tid >> 4;
  float acc[4][4];
  #pragma unroll
  for (int a=0;a<4;a++)
    #pragma unroll
    for (int b=0;b<4;b++) acc[a][b]=0.0f;

  for (int k0=0; k0<256; k0+=32){
    #pragma unroll
    for (int i=0;i<8;i++){
      int e = tid + i*256;
      int rl = e>>5, kl = e&31;
      int kk = kbase + k0 + kl;
      As[rl][kl] = fmaf(y1[(size_t)(m0+rl)*DMLP + kk], scale1[kk], shift1[kk]);
      Bs[rl][kl] = W2[(size_t)(n0+rl)*DMLP + kk];
    }
    __syncthreads();
    #pragma unroll
    for (int kk=0;kk<32;kk++){
      float a[4], w[4];
      #pragma unroll
      for (int rl=0;rl<4;rl++) a[rl] = As[ty*4+rl][kk];
      #pragma unroll
      for (int cj=0;cj<4;cj++) w[cj] = Bs[cj*16+tx][kk];
      #pragma unroll
      for (int rl=0;rl<4;rl++)
        #pragma unroll
        for (int cj=0;cj<4;cj++) acc[rl][cj] = fmaf(a[rl], w[cj], acc[rl][cj]);
    }
    __syncthreads();
  }
  float* dst = y2part + ((size_t)blockIdx.z*BATCH)*DMLP;
  #pragma unroll
  for (int rl=0;rl<4;rl++){
    int r = m0 + ty*4 + rl;
    #pragma unroll
    for (int cj=0;cj<4;cj++){
      int n = n0 + cj*16 + tx;
      dst[(size_t)r*DMLP + n] = acc[rl][cj];
    }
  }
}

// finalize: y2 = relu(sum_k y2part + bias)
__global__ __launch_bounds__(256) void k_mlp2_fin(
    const float* __restrict__ y2part, const float* __restrict__ b2,
    float* __restrict__ y2)
{
  const int b = blockIdx.x;
  const int n = threadIdx.x*4;
  float4 p0 = *(const float4*)(y2part + ((size_t)(0*BATCH + b))*DMLP + n);
  float4 p1 = *(const float4*)(y2part + ((size_t)(1*BATCH + b))*DMLP + n);
  float4 p2 = *(const float4*)(y2part + ((size_t)(2*BATCH + b))*DMLP + n);
  float4 p3 = *(const float4*)(y2part + ((size_t)(3*BATCH + b))*DMLP + n);
  float4 bb = *(const float4*)(b2 + n);
  float4 o;
  o.x = fmaxf(p0.x+p1.x+p2.x+p3.x+bb.x, 0.0f);
  o.y = fmaxf(p0.y+p1.y+p2.y+p3.y+bb.y, 0.0f);
  o.z = fmaxf(p0.z+p1.z+p2.z+p3.z+bb.z, 0.0f);
  o.w = fmaxf(p0.w+p1.w+p2.w+p3.w+bb.w, 0.0f);
  *(float4*)(y2 + (size_t)b*DMLP + n) = o;
}

__global__ __launch_bounds__(256) void k_mlp3(const float* __restrict__ y2,
    const float* __restrict__ scale2, const float* __restrict__ shift2,
    const float* __restrict__ W3, const float* __restrict__ b3,
    float* __restrict__ out)
{
  __shared__ float r0[256], r1[256];
  const int b = blockIdx.x, tid = threadIdx.x;
  float p0=0.0f, p1=0.0f;
  #pragma unroll
  for (int q=0;q<4;q++){
    int k = tid + q*256;
    float x = fmaf(y2[(size_t)b*DMLP + k], scale2[k], shift2[k]);
    p0 = fmaf(x, W3[k], p0);
    p1 = fmaf(x, W3[DMLP+k], p1);
  }
  r0[tid]=p0; r1[tid]=p1;
  __syncthreads();
  for (int s=128; s>0; s>>=1){
    if (tid<s){ r0[tid]+=r0[tid+s]; r1[tid]+=r1[tid+s]; }
    __syncthreads();
  }
  if (tid==0){
    float l0 = r0[0]+b3[0], l1 = r1[0]+b3[1];
    float m = fmaxf(l0,l1);
    float lse = m + logf(__expf(l0-m)+__expf(l1-m));
    out[b*2+0] = l0-lse;
    out[b*2+1] = l1-lse;
  }
}

// ---------------------------------------------------------------------------
extern "C" void kernel_launch(void* const* d_in, const int* in_sizes, int n_in,
                              void* d_out, int out_size, void* d_ws, size_t ws_size,
                              hipStream_t stream)
{
  (void)in_sizes; (void)n_in; (void)out_size; (void)ws_size;
  const float* embed = (const float*)d_in[0];
  const float* projW = (const float*)d_in[1];
  const float* projb = (const float*)d_in[2];
  const float* bn_g  = (const float*)d_in[3];
  const float* bn_b  = (const float*)d_in[4];
  const float* Wih   = (const float*)d_in[5];
  const float* Whh   = (const float*)d_in[6];
  const float* bih   = (const float*)d_in[7];
  const float* bhh   = (const float*)d_in[8];
  const float* W1    = (const float*)d_in[9];
  const float* b1    = (const float*)d_in[10];
  const float* g1    = (const float*)d_in[11];
  const float* be1   = (const float*)d_in[12];
  const float* W2    = (const float*)d_in[13];
  const float* b2    = (const float*)d_in[14];
  const float* g2    = (const float*)d_in[15];
  const float* be2   = (const float*)d_in[16];
  const float* W3    = (const float*)d_in[17];
  const float* b3    = (const float*)d_in[18];
  const float* extra = (const float*)d_in[19];
  const int*   s1    = (const int*)d_in[20];
  const int*   s2    = (const int*)d_in[21];
  float* out = (float*)d_out;

  float* ws = (float*)d_ws;
  size_t off = 0;
  float* ps   = ws + off; off += (size_t)2*60*EMB;
  float* psq  = ws + off; off += (size_t)2*60*EMB;
  float* bnsc = ws + off; off += 2*EMB;
  float* bnsh = ws + off; off += 2*EMB;
  float* bsum = ws + off; off += 2048;
  unsigned short* Pb     = (unsigned short*)(ws + off); off += (size_t)NROW*EMBP/2;
  unsigned short* Wihb   = (unsigned short*)(ws + off); off += (size_t)2048*EMBP/2;
  unsigned short* Whhb   = (unsigned short*)(ws + off); off += (size_t)2048*HID/2;
  unsigned short* projWb = (unsigned short*)(ws + off); off += (size_t)EMBP*EMBP/2;
  float* cst = ws + off; off += (size_t)512*HID;           // f32 c-state
  unsigned short* Hb0 = (unsigned short*)(ws + off); off += (size_t)512*HID/2;
  unsigned short* Hb1 = (unsigned short*)(ws + off); off += (size_t)512*HID/2;
  unsigned short* Hout = (unsigned short*)(ws + off); off += (size_t)2*S_LEN*BATCH*HID/2;
  float* pooled = ws + off; off += (size_t)BATCH*225;
  float* y1     = ws + off; off += (size_t)BATCH*DMLP;
  float* y2     = ws + off; off += (size_t)BATCH*DMLP;
  float* y2part = ws + off; off += (size_t)4*BATCH*DMLP;
  float* sc1    = ws + off; off += DMLP;
  float* sh1    = ws + off; off += DMLP;
  float* sc2    = ws + off; off += DMLP;
  float* sh2    = ws + off; off += DMLP;
  // total ~18M float-slots ~72 MB

  // zero c-state (f32) + Hb0 (bf16), contiguous
  hipMemsetAsync(cst, 0, (size_t)(512*HID)*sizeof(float) + (size_t)(512*HID)*sizeof(unsigned short), stream);

  k_conv_weights<<<512, 256, 0, stream>>>(Wih, Whh, bih, bhh, projW,
                                          Wihb, Whhb, projWb, bsum);
  k_embed_mfma<<<dim3(NROW/64, 5), 512, 0, stream>>>(embed, projWb, projb, s1, s2, Pb);
  k_bn_partial<<<dim3(60,2), 320, 0, stream>>>(Pb, ps, psq);
  k_bn_final<<<2, 320, 0, stream>>>(ps, psq, bn_g, bn_b, bnsc, bnsh);
  k_bn_apply<<<NROW/8, 256, 0, stream>>>(Pb, bnsc, bnsh);

  for (int t=0; t<S_LEN; t++){
    const unsigned short* hin = (t & 1) ? Hb1 : Hb0;
    unsigned short*      hnxt = (t & 1) ? Hb0 : Hb1;
    k_lstm_step<<<dim3(32,8), 512, 0, stream>>>(Pb, Wihb, Whhb, bsum,
                                                hin, hnxt, cst, Hout, t);
  }

  k_dist_pool<<<BATCH, 256, 0, stream>>>(Hout, pooled);
  k_mlp1<<<BATCH, 256, 0, stream>>>(pooled, extra, W1, b1, y1);
  k_mlp_bn2<<<16, 256, 0, stream>>>(y1, g1, be1, sc1, sh1);
  k_mlp2_gemm<<<dim3(16,4,4), 256, 0, stream>>>(y1, sc1, sh1, W2, y2part);
  k_mlp2_fin<<<BATCH, 256, 0, stream>>>(y2part, b2, y2);
  k_mlp_bn2<<<16, 256, 0, stream>>>(y2, g2, be2, sc2, sh2);
  k_mlp3<<<BATCH, 256, 0, stream>>>(y2, sc2, sh2, W3, b3, out);
}